// Round 7
// baseline (482.304 us; speedup 1.0000x reference)
//
#include <hip/hip_runtime.h>

// SNN forward, round 7.
// convV: weights held in VGPRs (192/wave, persistent) — zero steady-state A
// traffic. 4 waves = (ct x tap-half); 6 real pos-tiles per wave; tap-half
// partials combined via 52KB LDS exchange (2-way swizzle). Staging by th1
// waves overlaps th0 epilogue. Two barriers/item.

typedef __attribute__((ext_vector_type(8))) _Float16 v8h;
typedef __attribute__((ext_vector_type(16))) float v16f;
typedef _Float16 half_t;

#define NB 32
#define NC 64
#define NT 129
#define TIN 128
#define NM 40
#define MSTR 136          // LDS per-slot stride: conflict-free (0 conflicts measured)
#define SROWB 5120        // global spike row bytes = 40*64*2
#define XTILE 4352        // exchange tile bytes = 32*136
#define XCT 26112         // 6*XTILE

// ---- weights -> MFMA A-fragments (single copy), order [tap12][cq4][ct2][hl2][lane64] ----
__global__ void prep_wfrag2(const float* __restrict__ w2, const float* __restrict__ w3,
                            uint4* __restrict__ wfA, uint4* __restrict__ wfB) {
    int tid = blockIdx.x * 256 + threadIdx.x;   // 24576
    if (tid >= 24576) return;
    const float* w = (tid < 12288) ? w2 : w3;
    uint4* wf = (tid < 12288) ? wfA : wfB;
    int t2 = (tid < 12288) ? tid : tid - 12288;
    int lane = t2 & 63;
    int rest = t2 >> 6;
    int hl = rest & 1;
    int ct = (rest >> 1) & 1;
    int cq = (rest >> 2) & 3;
    int tap = rest >> 4;
    int kh = tap / 3, kw = tap % 3;
    int co = ct * 32 + (lane & 31);
    unsigned short o[8];
#pragma unroll
    for (int jj = 0; jj < 8; jj++) {
        int ci = cq * 16 + (lane >> 5) * 8 + jj;
        float wv = w[((co * 64 + ci) * 4 + kh) * 3 + kw];
        _Float16 hi = (_Float16)wv;
        _Float16 val = hl ? (_Float16)((wv - (float)hi) * 2048.0f) : hi;
        unsigned short us;
        __builtin_memcpy(&us, &val, 2);
        o[jj] = us;
    }
    uint4 r;
    __builtin_memcpy(&r, o, 16);
    wf[t2] = r;
}

// ---- conv1 (1->64ch, 4x3, pad(2,1)) + LIF1, unroll-8 row prefetch ----
__global__ void conv1_lif1(const float* __restrict__ x, const float* __restrict__ w1,
                           half_t* __restrict__ s1) {
    const int mg = blockIdx.x;        // 0..9
    const int b = blockIdx.y;
    const int c = threadIdx.x & 63;
    const int ml = threadIdx.x >> 6;  // 0..3
    const int m = mg * 4 + ml;
    float w[4][3];
#pragma unroll
    for (int kh = 0; kh < 4; kh++)
#pragma unroll
        for (int kw = 0; kw < 3; kw++) w[kh][kw] = w1[(c * 4 + kh) * 3 + kw];
    const float* xb = x + (size_t)b * TIN * NM;

    float xw[12][3];
#pragma unroll
    for (int rr = 0; rr < 12; rr++)
#pragma unroll
        for (int kw = 0; kw < 3; kw++) xw[rr][kw] = 0.f;
#pragma unroll
    for (int rr = 2; rr < 4; rr++)
#pragma unroll
        for (int kw = 0; kw < 3; kw++) {
            int mc = m - 1 + kw;
            xw[rr][kw] = ((unsigned)mc < (unsigned)NM) ? xb[(rr - 2) * NM + mc] : 0.f;
        }

    half_t* orow = s1 + ((size_t)b * NT * NM + m) * 64 + c;
    float v = 0.f;
    const float TAUc = 10.0f / 7.0f;

    for (int tb = 0; tb < NT; tb += 8) {
#pragma unroll
        for (int q = 0; q < 8; q++) {
            int row = tb + 2 + q;
#pragma unroll
            for (int kw = 0; kw < 3; kw++) {
                int mc = m - 1 + kw;
                xw[4 + q][kw] = (row < TIN && (unsigned)mc < (unsigned)NM)
                                    ? xb[row * NM + mc] : 0.f;
            }
        }
        int kmax = (NT - tb) < 8 ? (NT - tb) : 8;
#pragma unroll
        for (int k = 0; k < 8; k++) {
            if (k < kmax) {
                float uacc = 0.f;
#pragma unroll
                for (int kh = 0; kh < 4; kh++)
#pragma unroll
                    for (int kw = 0; kw < 3; kw++) uacc += xw[k + kh][kw] * w[kh][kw];
                v = v + (uacc - v) / TAUc;
                float s = (v >= 1.0f) ? 1.0f : 0.0f;
                orow[(size_t)(tb + k) * NM * 64] = (half_t)s;
                if (v >= 1.0f) v = 0.0f;
            }
        }
#pragma unroll
        for (int rr = 0; rr < 4; rr++)
#pragma unroll
            for (int kw = 0; kw < 3; kw++) xw[rr][kw] = xw[8 + rr][kw];
    }
}

// ---- item decode: g -> (b, r, j0); 33 items per b ----
template <int RSH>
__device__ __forceinline__ void decode_item(int g, int& b, int& r, int& j0) {
    int bx = g % 33;
    b = g / 33;
    if (bx < 32) { r = bx & ((1 << RSH) - 1); j0 = (bx >> RSH) * 4; }
    else         { r = 0;                     j0 = (32 >> RSH) * 4; }
}

// ---- spike staging by th1 waves (sid 0,1), zero-fill OOB ----
template <int DH, int PH, int PW, int EXT, int KSTG>
__device__ __forceinline__ void stageV(char* lds, const half_t* __restrict__ spk,
                                       int b, int r, int j0, int sid, int lane) {
    constexpr int NCH = 7 * EXT * 8;
    constexpr int LROWB = EXT * MSTR;
    const char* spb = (const char*)spk + (size_t)b * NT * SROWB;
    uint4 R[KSTG];
#pragma unroll
    for (int k = 0; k < KSTG; k++) {
        int c = k * 128 + sid * 64 + lane;
        uint4 val = make_uint4(0u, 0u, 0u, 0u);
        if (c < NCH) {
            int i = c / (EXT * 8);
            int rem = c - i * (EXT * 8);
            int s = rem >> 3;
            int ci8 = rem & 7;
            int tg = r - PH + DH * (j0 + i);
            int md = s - PW;
            if ((unsigned)tg < (unsigned)NT && (unsigned)md < (unsigned)NM)
                val = *(const uint4*)(spb + ((size_t)tg * NM + md) * 128 + ci8 * 16);
        }
        R[k] = val;
    }
#pragma unroll
    for (int k = 0; k < KSTG; k++) {
        int c = k * 128 + sid * 64 + lane;
        if (c < NCH) {
            int i = c / (EXT * 8);
            int rem = c - i * (EXT * 8);
            int s = rem >> 3;
            int ci8 = rem & 7;
            *(uint4*)(lds + i * LROWB + s * MSTR + ci8 * 16) = R[k];
        }
    }
}

// ---- K-loop: 6 taps x 4 cq, A from registers, B from LDS ----
template <int TH, int LROWB, int DWM>
__device__ __forceinline__ void do_compute(const char* __restrict__ buf, const int* baseB,
                                           const v8h A[6][4][2], v16f acc[6][2]) {
#pragma unroll
    for (int tt = 0; tt < 6; tt++) {
        const int tap = TH * 6 + tt;
        const int kh = tap / 3, kw = tap % 3;
        const int bo = kh * LROWB + kw * DWM;
#pragma unroll
        for (int cq = 0; cq < 4; cq++) {
            v8h B[6];
#pragma unroll
            for (int tau = 0; tau < 6; tau++)
                B[tau] = *(const v8h*)(buf + baseB[tau] + bo + cq * 32);
#pragma unroll
            for (int tau = 0; tau < 6; tau++) {
                acc[tau][0] = __builtin_amdgcn_mfma_f32_32x32x16_f16(A[tt][cq][0], B[tau], acc[tau][0], 0, 0, 0);
                acc[tau][1] = __builtin_amdgcn_mfma_f32_32x32x16_f16(A[tt][cq][1], B[tau], acc[tau][1], 0, 0, 0);
            }
        }
    }
}

// ---- persistent weights-in-VGPR MFMA conv ----
template <int DH, int PH, int DW, int PW, int EXT, int RSH, int KSTG>
__global__ __launch_bounds__(256, 1) void convV(const half_t* __restrict__ spk,
                                                const uint4* __restrict__ wfrag,
                                                float* __restrict__ u, int totItems) {
    extern __shared__ char lds[];
    constexpr int LROWB = EXT * MSTR;
    constexpr int SP = 7 * LROWB;               // exchange region starts here
    const int tid = threadIdx.x;
    const int lane = tid & 63;
    const int wv = tid >> 6;
    const int ct = wv >> 1;                     // co-tile
    const int th = wv & 1;                      // tap half
    const int sid = wv >> 1;                    // staging id for th1 waves

    // ---- A fragments: 48 per wave, permanent VGPR residents ----
    v8h A[6][4][2];
#pragma unroll
    for (int tt = 0; tt < 6; tt++)
#pragma unroll
        for (int cq = 0; cq < 4; cq++)
#pragma unroll
            for (int hl = 0; hl < 2; hl++) {
                int tap = th * 6 + tt;
                A[tt][cq][hl] = *(const v8h*)(wfrag +
                    (size_t)((tap * 4 + cq) * 4 + ct * 2 + hl) * 64 + lane);
            }

    // ---- lane decode: 6 pos-tiles (2j x 16m each) ----
    const int pos = lane & 31;
    const int jlocal = pos >> 4;
    const int mloc = pos & 15;
    const int hseg = lane >> 5;
    int baseB[6], mmv[6], jv[6];
#pragma unroll
    for (int tau = 0; tau < 6; tau++) {
        int jp = tau / 3, mc = tau - 3 * jp;
        int j = 2 * jp + jlocal;
        int m = mc * 16 + mloc;
        int meff = m > 39 ? 39 : m;
        baseB[tau] = j * LROWB + meff * MSTR + hseg * 16;
        mmv[tau] = m; jv[tau] = j;
    }

    int g = blockIdx.x;
    int cb, cr, cj0;
    decode_item<RSH>(g, cb, cr, cj0);
    if (th == 1) stageV<DH, PH, PW, EXT, KSTG>(lds, spk, cb, cr, cj0, sid, lane);
    __syncthreads();

    const float invs = 1.0f / 2048.0f;
    const int xsw = (lane >> 1) * 136 + (lane & 1) * 64;   // exchange swizzle base
    while (true) {
        v16f acc[6][2];
#pragma unroll
        for (int a = 0; a < 6; a++)
#pragma unroll
            for (int h = 0; h < 2; h++) acc[a][h] = (v16f)(0.0f);

        if (th == 0) do_compute<0, LROWB, DW * MSTR>(lds, baseB, A, acc);
        else         do_compute<1, LROWB, DW * MSTR>(lds, baseB, A, acc);

        // fold hi/lo: acc[tau][0] += acc[tau][1]/2048
#pragma unroll
        for (int tau = 0; tau < 6; tau++)
#pragma unroll
            for (int i = 0; i < 16; i++)
                acc[tau][0][i] = acc[tau][0][i] + acc[tau][1][i] * invs;

        if (th == 1) {                           // write tap-half partial to LDS
#pragma unroll
            for (int tau = 0; tau < 6; tau++)
#pragma unroll
                for (int gg = 0; gg < 4; gg++) {
                    float4 val = make_float4(acc[tau][0][4 * gg + 0], acc[tau][0][4 * gg + 1],
                                             acc[tau][0][4 * gg + 2], acc[tau][0][4 * gg + 3]);
                    *(float4*)(lds + SP + ct * XCT + tau * XTILE + xsw + gg * 16) = val;
                }
        }
        __syncthreads();

        int gn = g + (int)gridDim.x;
        bool hn = gn < totItems;
        int nb = 0, nr = 0, nj0 = 0;
        if (th == 1) {                           // stage next item (spike region free)
            if (hn) {
                decode_item<RSH>(gn, nb, nr, nj0);
                stageV<DH, PH, PW, EXT, KSTG>(lds, spk, nb, nr, nj0, sid, lane);
            }
        } else {                                 // combine halves + store u
#pragma unroll
            for (int tau = 0; tau < 6; tau++) {
                int t = cr + DH * (cj0 + jv[tau]);
                if (mmv[tau] < NM && t < NT) {
                    float* base = u + ((size_t)(cb * NT + t) * NM + mmv[tau]) * 64;
#pragma unroll
                    for (int gg = 0; gg < 4; gg++) {
                        float4 rv = *(float4*)(lds + SP + ct * XCT + tau * XTILE + xsw + gg * 16);
                        float4 val;
                        val.x = acc[tau][0][4 * gg + 0] + rv.x;
                        val.y = acc[tau][0][4 * gg + 1] + rv.y;
                        val.z = acc[tau][0][4 * gg + 2] + rv.z;
                        val.w = acc[tau][0][4 * gg + 3] + rv.w;
                        *(float4*)(base + ct * 32 + 8 * gg + 4 * hseg) = val;
                    }
                }
            }
        }
        __syncthreads();
        if (!hn) break;
        g = gn; cb = nb; cr = nr; cj0 = nj0;
    }
}

// ---- LIF over T: u fp32 -> compact f16 spikes, unroll-16 ----
__global__ void lif_spikes(const float* __restrict__ u, half_t* __restrict__ s2) {
    int tid = blockIdx.x * 256 + threadIdx.x;   // 81920
    int b = tid / 2560;
    int cm = tid % 2560;
    const float* up = u + (size_t)b * NT * 2560 + cm;
    half_t* sp = s2 + (size_t)b * NT * 2560 + cm;
    float v = 0.f;
    const float TAUc = 10.0f / 7.0f;
    for (int tb = 0; tb < 128; tb += 16) {
        float uu[16];
#pragma unroll
        for (int k = 0; k < 16; k++) uu[k] = up[(size_t)(tb + k) * 2560];
#pragma unroll
        for (int k = 0; k < 16; k++) {
            v = v + (uu[k] - v) / TAUc;
            float s = (v >= 1.0f) ? 1.0f : 0.0f;
            sp[(size_t)(tb + k) * 2560] = (half_t)s;
            if (v >= 1.0f) v = 0.f;
        }
    }
    float uu = up[(size_t)128 * 2560];
    v = v + (uu - v) / TAUc;
    sp[(size_t)128 * 2560] = (half_t)((v >= 1.0f) ? 1.0f : 0.0f);
}

// ---- LIF3: spike counts only (mean commutes with FC), unroll-16 ----
__global__ void lif_sum(const float* __restrict__ u, float* __restrict__ hsum) {
    int tid = blockIdx.x * 256 + threadIdx.x;   // 81920
    int b = tid / 2560;
    int cm = tid % 2560;                         // = m*64 + co
    int m = cm >> 6;
    int co = cm & 63;
    const float* up = u + (size_t)b * NT * 2560 + cm;
    float v = 0.f, cnt = 0.f;
    const float TAUc = 10.0f / 7.0f;
    for (int tb = 0; tb < 128; tb += 16) {
        float uu[16];
#pragma unroll
        for (int k = 0; k < 16; k++) uu[k] = up[(size_t)(tb + k) * 2560];
#pragma unroll
        for (int k = 0; k < 16; k++) {
            v = v + (uu[k] - v) / TAUc;
            if (v >= 1.0f) { cnt += 1.0f; v = 0.f; }
        }
    }
    float uu = up[(size_t)128 * 2560];
    v = v + (uu - v) / TAUc;
    if (v >= 1.0f) cnt += 1.0f;
    hsum[b * 2560 + co * NM + m] = cnt;          // feature index = c*40 + m
}

// ---- FC on counts: y[b,k] = bf[k] + (sum_cm cnt*wf[k,cm]) / 129 ----
__global__ void fc_out(const float* __restrict__ hsum, const float* __restrict__ wf,
                       const float* __restrict__ bfv, float* __restrict__ out) {
    int b = blockIdx.x;
    int tid = threadIdx.x;
    float p[12];
#pragma unroll
    for (int k = 0; k < 12; k++) p[k] = 0.0f;
    for (int cm = tid; cm < NC * NM; cm += 256) {
        float h = hsum[b * NC * NM + cm];
#pragma unroll
        for (int k = 0; k < 12; k++) p[k] += h * wf[k * (NC * NM) + cm];
    }
    __shared__ float red[12][4];
    int lane = tid & 63, w = tid >> 6;
#pragma unroll
    for (int k = 0; k < 12; k++) {
        float s = p[k];
#pragma unroll
        for (int off = 32; off > 0; off >>= 1) s += __shfl_down(s, off, 64);
        if (lane == 0) red[k][w] = s;
    }
    __syncthreads();
    if (tid < 12) {
        float s = red[tid][0] + red[tid][1] + red[tid][2] + red[tid][3];
        out[b * 12 + tid] = bfv[tid] + s / 129.0f;
    }
}

extern "C" void kernel_launch(void* const* d_in, const int* in_sizes, int n_in,
                              void* d_out, int out_size, void* d_ws, size_t ws_size,
                              hipStream_t stream) {
    const float* x  = (const float*)d_in[0];
    const float* w1 = (const float*)d_in[1];
    const float* w2 = (const float*)d_in[2];
    const float* w3 = (const float*)d_in[3];
    const float* wf = (const float*)d_in[4];
    const float* bf = (const float*)d_in[5];
    float* out = (float*)d_out;

    char* ws = (char*)d_ws;
    half_t* s1  = (half_t*)ws;                      // 21,135,360 B
    half_t* s2  = (half_t*)(ws + 21135360);         // 21,135,360 B
    float*  u   = (float*)(ws + 42270720);          // 42,270,720 B
    uint4*  wf2 = (uint4*)(ws + 84541440);          // 196,608 B
    uint4*  wf3 = (uint4*)(ws + 84738048);          // 196,608 B
    float* hsum = (float*)(ws + 84934656);          // 327,680 B (end ~85.3 MB)

    // LDS: spikes 7*EXT*136 + exchange 2*6*4352
    constexpr int LDS2 = 7 * 46 * MSTR + 2 * XCT;   // 43792 + 52224 = 96,016
    constexpr int LDS3 = 7 * 58 * MSTR + 2 * XCT;   // 55216 + 52224 = 107,440
    static bool attr_set = false;
    if (!attr_set) {
        hipFuncSetAttribute((const void*)&convV<4, 6, 3, 3, 46, 2, 21>,
                            hipFuncAttributeMaxDynamicSharedMemorySize, LDS2);
        hipFuncSetAttribute((const void*)&convV<16, 24, 9, 9, 58, 4, 26>,
                            hipFuncAttributeMaxDynamicSharedMemorySize, LDS3);
        attr_set = true;
    }

    prep_wfrag2<<<96, 256, 0, stream>>>(w2, w3, wf2, wf3);

    conv1_lif1<<<dim3(10, 32), 256, 0, stream>>>(x, w1, s1);

    convV<4, 6, 3, 3, 46, 2, 21><<<256, 256, LDS2, stream>>>(s1, wf2, u, 1056);
    lif_spikes<<<320, 256, 0, stream>>>(u, s2);

    convV<16, 24, 9, 9, 58, 4, 26><<<256, 256, LDS3, stream>>>(s2, wf3, u, 1056);
    lif_sum<<<320, 256, 0, stream>>>(u, hsum);

    fc_out<<<32, 256, 0, stream>>>(hsum, wf, bf, out);
}

// Round 8
// 395.464 us; speedup vs baseline: 1.2196x; 1.2196x over previous
//
#include <hip/hip_runtime.h>

// SNN forward, round 8.
// convL: A-fragments staged in LDS (shared across waves, reused all item);
// hi/lo weight planes split across BLOCKS (blockIdx.z); u = u_hi + u_lo/2048
// folded into the LIF kernels (per-acc accumulation order unchanged -> same u).
// 4 waves x 3 pos-tiles x 2 ct = 6 accs (96 reg). Per (tap,cq): 2 A + 3 B
// ds_reads feed 6 MFMA — at the LDS/MFMA balance point. No dummy tiles.

typedef __attribute__((ext_vector_type(8))) _Float16 v8h;
typedef __attribute__((ext_vector_type(16))) float v16f;
typedef _Float16 half_t;

#define NB 32
#define NC 64
#define NT 129
#define TIN 128
#define NM 40
#define MSTR 136          // LDS per-slot stride: conflict-free (0 conflicts measured)
#define SROWB 5120        // global spike row bytes = 40*64*2

// ---- weights -> MFMA A-fragments, order [tap12][cq4][ct2][hl2][lane64]x16B ----
// A-frag (32x32x16 f16): lane holds A[co=ct*32+(lane&31)][ci=cq*16+(lane>>5)*8+jj]
__global__ void prep_wfrag2(const float* __restrict__ w2, const float* __restrict__ w3,
                            uint4* __restrict__ wfA, uint4* __restrict__ wfB) {
    int tid = blockIdx.x * 256 + threadIdx.x;   // 24576
    if (tid >= 24576) return;
    const float* w = (tid < 12288) ? w2 : w3;
    uint4* wf = (tid < 12288) ? wfA : wfB;
    int t2 = (tid < 12288) ? tid : tid - 12288;
    int lane = t2 & 63;
    int rest = t2 >> 6;
    int hl = rest & 1;
    int ct = (rest >> 1) & 1;
    int cq = (rest >> 2) & 3;
    int tap = rest >> 4;
    int kh = tap / 3, kw = tap % 3;
    int co = ct * 32 + (lane & 31);
    unsigned short o[8];
#pragma unroll
    for (int jj = 0; jj < 8; jj++) {
        int ci = cq * 16 + (lane >> 5) * 8 + jj;
        float wv = w[((co * 64 + ci) * 4 + kh) * 3 + kw];
        _Float16 hi = (_Float16)wv;
        _Float16 val = hl ? (_Float16)((wv - (float)hi) * 2048.0f) : hi;
        unsigned short us;
        __builtin_memcpy(&us, &val, 2);
        o[jj] = us;
    }
    uint4 r;
    __builtin_memcpy(&r, o, 16);
    wf[t2] = r;
}

// ---- conv1 (1->64ch, 4x3, pad(2,1)) + LIF1, unroll-8 row prefetch ----
__global__ void conv1_lif1(const float* __restrict__ x, const float* __restrict__ w1,
                           half_t* __restrict__ s1) {
    const int mg = blockIdx.x;        // 0..9
    const int b = blockIdx.y;
    const int c = threadIdx.x & 63;
    const int ml = threadIdx.x >> 6;  // 0..3
    const int m = mg * 4 + ml;
    float w[4][3];
#pragma unroll
    for (int kh = 0; kh < 4; kh++)
#pragma unroll
        for (int kw = 0; kw < 3; kw++) w[kh][kw] = w1[(c * 4 + kh) * 3 + kw];
    const float* xb = x + (size_t)b * TIN * NM;

    float xw[12][3];
#pragma unroll
    for (int rr = 0; rr < 12; rr++)
#pragma unroll
        for (int kw = 0; kw < 3; kw++) xw[rr][kw] = 0.f;
#pragma unroll
    for (int rr = 2; rr < 4; rr++)
#pragma unroll
        for (int kw = 0; kw < 3; kw++) {
            int mc = m - 1 + kw;
            xw[rr][kw] = ((unsigned)mc < (unsigned)NM) ? xb[(rr - 2) * NM + mc] : 0.f;
        }

    half_t* orow = s1 + ((size_t)b * NT * NM + m) * 64 + c;
    float v = 0.f;
    const float TAUc = 10.0f / 7.0f;

    for (int tb = 0; tb < NT; tb += 8) {
#pragma unroll
        for (int q = 0; q < 8; q++) {
            int row = tb + 2 + q;
#pragma unroll
            for (int kw = 0; kw < 3; kw++) {
                int mc = m - 1 + kw;
                xw[4 + q][kw] = (row < TIN && (unsigned)mc < (unsigned)NM)
                                    ? xb[row * NM + mc] : 0.f;
            }
        }
        int kmax = (NT - tb) < 8 ? (NT - tb) : 8;
#pragma unroll
        for (int k = 0; k < 8; k++) {
            if (k < kmax) {
                float uacc = 0.f;
#pragma unroll
                for (int kh = 0; kh < 4; kh++)
#pragma unroll
                    for (int kw = 0; kw < 3; kw++) uacc += xw[k + kh][kw] * w[kh][kw];
                v = v + (uacc - v) / TAUc;
                float s = (v >= 1.0f) ? 1.0f : 0.0f;
                orow[(size_t)(tb + k) * NM * 64] = (half_t)s;
                if (v >= 1.0f) v = 0.0f;
            }
        }
#pragma unroll
        for (int rr = 0; rr < 4; rr++)
#pragma unroll
            for (int kw = 0; kw < 3; kw++) xw[rr][kw] = xw[8 + rr][kw];
    }
}

// ---- MFMA conv 64->64, 4x3 dilated; A in LDS, hl split across blocks ----
// grid (17, 32, 2). bx<16: r=bx%RMOD, jj0=(bx/RMOD)*8; bx=16: r=0, jj0=(16/RMOD)*8.
// z = hl. 256 thr = 4 waves; wave w owns jp=w (j = 2w,2w+1) x 3 m-tiles.
template <int DH, int PH, int DW, int PW, int EXT, int RMOD, int NSTG>
__global__ __launch_bounds__(256, 1) void convL(const half_t* __restrict__ spk,
                                                const uint4* __restrict__ wfrag,
                                                float* __restrict__ u_hi,
                                                float* __restrict__ u_lo) {
    extern __shared__ char lds[];
    constexpr int LROWB = EXT * MSTR;
    constexpr int ALDS = 11 * LROWB;            // A region after 11 spike rows
    constexpr int NCH = 11 * EXT * 8;           // spike staging chunks (16B)
    const int tid = threadIdx.x;
    const int lane = tid & 63;
    const int wv = tid >> 6;                    // 0..3 = jp
    const int bx = blockIdx.x;
    const int b = blockIdx.y;
    const int hl = blockIdx.z;
    int r, jj0;
    if (bx < 16) { r = bx % RMOD; jj0 = (bx / RMOD) * 8; }
    else         { r = 0;         jj0 = (16 / RMOD) * 8; }

    // ---- stage 11 spike lattice rows (zero-fill OOB) ----
    const char* spb = (const char*)spk + (size_t)b * NT * SROWB;
#pragma unroll
    for (int k = 0; k < NSTG; k++) {
        int c = tid + k * 256;
        if (c < NCH) {
            int i = c / (EXT * 8);
            int rem = c - i * (EXT * 8);
            int s = rem >> 3;
            int ci8 = rem & 7;
            int tg = r - PH + DH * (jj0 + i);
            int md = s - PW;
            uint4 val = make_uint4(0u, 0u, 0u, 0u);
            if ((unsigned)tg < (unsigned)NT && (unsigned)md < (unsigned)NM)
                val = *(const uint4*)(spb + ((size_t)tg * NM + md) * 128 + ci8 * 16);
            *(uint4*)(lds + i * LROWB + s * MSTR + ci8 * 16) = val;
        }
    }
    // ---- stage this hl's 48 A-fragments (48 KB) ----
#pragma unroll
    for (int k = 0; k < 12; k++) {
        int idx = tid + k * 256;                // 0..3071 = frag*64 + lane_s
        int frag = idx >> 6;                    // (tap*4+cq)*2 + ct
        int lane_s = idx & 63;
        uint4 val = wfrag[(size_t)(frag * 2 + hl) * 64 + lane_s];
        *(uint4*)(lds + ALDS + idx * 16) = val;
    }
    __syncthreads();

    // ---- lane decode: wave = jp; tiles = 3 m-chunks of (2j x 16m) ----
    const int pos = lane & 31;
    const int jlocal = pos >> 4;
    const int mloc = pos & 15;
    const int hseg = lane >> 5;
    const int j = 2 * wv + jlocal;              // 0..7 (LDS row == j)
    int baseB[3], mv[3];
#pragma unroll
    for (int mc = 0; mc < 3; mc++) {
        int m = mc * 16 + mloc;                 // 0..47
        int meff = m > 39 ? 39 : m;
        baseB[mc] = j * LROWB + meff * MSTR + hseg * 16;
        mv[mc] = m;
    }

    v16f acc[3][2];                             // [m-tile][co-tile]
#pragma unroll
    for (int a = 0; a < 3; a++)
#pragma unroll
        for (int c = 0; c < 2; c++) acc[a][c] = (v16f)(0.0f);

#pragma unroll
    for (int tap = 0; tap < 12; tap++) {
        const int kh = tap / 3, kw = tap % 3;
        const int bo = kh * LROWB + kw * (DW * MSTR);
#pragma unroll
        for (int cq = 0; cq < 4; cq++) {
            v8h B0 = *(const v8h*)(lds + baseB[0] + bo + cq * 32);
            v8h B1 = *(const v8h*)(lds + baseB[1] + bo + cq * 32);
            v8h B2 = *(const v8h*)(lds + baseB[2] + bo + cq * 32);
            const char* ab = lds + ALDS + (size_t)((tap * 4 + cq) * 2) * 1024 + lane * 16;
            v8h A0 = *(const v8h*)(ab);         // ct0
            v8h A1 = *(const v8h*)(ab + 1024);  // ct1
            acc[0][0] = __builtin_amdgcn_mfma_f32_32x32x16_f16(A0, B0, acc[0][0], 0, 0, 0);
            acc[0][1] = __builtin_amdgcn_mfma_f32_32x32x16_f16(A1, B0, acc[0][1], 0, 0, 0);
            acc[1][0] = __builtin_amdgcn_mfma_f32_32x32x16_f16(A0, B1, acc[1][0], 0, 0, 0);
            acc[1][1] = __builtin_amdgcn_mfma_f32_32x32x16_f16(A1, B1, acc[1][1], 0, 0, 0);
            acc[2][0] = __builtin_amdgcn_mfma_f32_32x32x16_f16(A0, B2, acc[2][0], 0, 0, 0);
            acc[2][1] = __builtin_amdgcn_mfma_f32_32x32x16_f16(A1, B2, acc[2][1], 0, 0, 0);
        }
    }

    // ---- epilogue: raw plane writes (combine happens in LIF) ----
    float* uout = hl ? u_lo : u_hi;
    const int t = r + DH * (jj0 + j);
#pragma unroll
    for (int mc = 0; mc < 3; mc++) {
        if (mv[mc] < NM && t < NT) {
            float* base = uout + ((size_t)(b * NT + t) * NM + mv[mc]) * 64;
#pragma unroll
            for (int ct = 0; ct < 2; ct++) {
#pragma unroll
                for (int g = 0; g < 4; g++) {
                    int co = ct * 32 + 8 * g + 4 * hseg;  // D row map
                    float4 val;
                    val.x = acc[mc][ct][4 * g + 0];
                    val.y = acc[mc][ct][4 * g + 1];
                    val.z = acc[mc][ct][4 * g + 2];
                    val.w = acc[mc][ct][4 * g + 3];
                    *(float4*)(base + co) = val;
                }
            }
        }
    }
}

// ---- LIF over T: u = u_hi + u_lo/2048 -> compact f16 spikes, unroll-16 ----
__global__ void lif_spikes(const float* __restrict__ uh, const float* __restrict__ ul,
                           half_t* __restrict__ s2) {
    int tid = blockIdx.x * 256 + threadIdx.x;   // 81920
    int b = tid / 2560;
    int cm = tid % 2560;
    size_t base = (size_t)b * NT * 2560 + cm;
    const float* uph = uh + base;
    const float* upl = ul + base;
    half_t* sp = s2 + base;
    float v = 0.f;
    const float TAUc = 10.0f / 7.0f;
    const float invs = 1.0f / 2048.0f;
    for (int tb = 0; tb < 128; tb += 16) {
        float uu[16];
#pragma unroll
        for (int k = 0; k < 16; k++)
            uu[k] = uph[(size_t)(tb + k) * 2560] + upl[(size_t)(tb + k) * 2560] * invs;
#pragma unroll
        for (int k = 0; k < 16; k++) {
            v = v + (uu[k] - v) / TAUc;
            float s = (v >= 1.0f) ? 1.0f : 0.0f;
            sp[(size_t)(tb + k) * 2560] = (half_t)s;
            if (v >= 1.0f) v = 0.f;
        }
    }
    float uu = uph[(size_t)128 * 2560] + upl[(size_t)128 * 2560] * invs;
    v = v + (uu - v) / TAUc;
    sp[(size_t)128 * 2560] = (half_t)((v >= 1.0f) ? 1.0f : 0.0f);
}

// ---- LIF3: spike counts only (mean commutes with FC), unroll-16 ----
__global__ void lif_sum(const float* __restrict__ uh, const float* __restrict__ ul,
                        float* __restrict__ hsum) {
    int tid = blockIdx.x * 256 + threadIdx.x;   // 81920
    int b = tid / 2560;
    int cm = tid % 2560;                         // = m*64 + co
    int m = cm >> 6;
    int co = cm & 63;
    size_t base = (size_t)b * NT * 2560 + cm;
    const float* uph = uh + base;
    const float* upl = ul + base;
    float v = 0.f, cnt = 0.f;
    const float TAUc = 10.0f / 7.0f;
    const float invs = 1.0f / 2048.0f;
    for (int tb = 0; tb < 128; tb += 16) {
        float uu[16];
#pragma unroll
        for (int k = 0; k < 16; k++)
            uu[k] = uph[(size_t)(tb + k) * 2560] + upl[(size_t)(tb + k) * 2560] * invs;
#pragma unroll
        for (int k = 0; k < 16; k++) {
            v = v + (uu[k] - v) / TAUc;
            if (v >= 1.0f) { cnt += 1.0f; v = 0.f; }
        }
    }
    float uu = uph[(size_t)128 * 2560] + upl[(size_t)128 * 2560] * invs;
    v = v + (uu - v) / TAUc;
    if (v >= 1.0f) cnt += 1.0f;
    hsum[b * 2560 + co * NM + m] = cnt;          // feature index = c*40 + m
}

// ---- FC on counts: y[b,k] = bf[k] + (sum_cm cnt*wf[k,cm]) / 129 ----
__global__ void fc_out(const float* __restrict__ hsum, const float* __restrict__ wf,
                       const float* __restrict__ bfv, float* __restrict__ out) {
    int b = blockIdx.x;
    int tid = threadIdx.x;
    float p[12];
#pragma unroll
    for (int k = 0; k < 12; k++) p[k] = 0.0f;
    for (int cm = tid; cm < NC * NM; cm += 256) {
        float h = hsum[b * NC * NM + cm];
#pragma unroll
        for (int k = 0; k < 12; k++) p[k] += h * wf[k * (NC * NM) + cm];
    }
    __shared__ float red[12][4];
    int lane = tid & 63, w = tid >> 6;
#pragma unroll
    for (int k = 0; k < 12; k++) {
        float s = p[k];
#pragma unroll
        for (int off = 32; off > 0; off >>= 1) s += __shfl_down(s, off, 64);
        if (lane == 0) red[k][w] = s;
    }
    __syncthreads();
    if (tid < 12) {
        float s = red[tid][0] + red[tid][1] + red[tid][2] + red[tid][3];
        out[b * 12 + tid] = bfv[tid] + s / 129.0f;
    }
}

extern "C" void kernel_launch(void* const* d_in, const int* in_sizes, int n_in,
                              void* d_out, int out_size, void* d_ws, size_t ws_size,
                              hipStream_t stream) {
    const float* x  = (const float*)d_in[0];
    const float* w1 = (const float*)d_in[1];
    const float* w2 = (const float*)d_in[2];
    const float* w3 = (const float*)d_in[3];
    const float* wf = (const float*)d_in[4];
    const float* bf = (const float*)d_in[5];
    float* out = (float*)d_out;

    char* ws = (char*)d_ws;
    half_t* s1  = (half_t*)ws;                      // 21,135,360 B
    half_t* s2  = (half_t*)(ws + 21135360);         // 21,135,360 B
    float*  uh  = (float*)(ws + 42270720);          // 42,270,720 B
    float*  ul  = (float*)(ws + 84541440);          // 42,270,720 B
    uint4*  wf2 = (uint4*)(ws + 126812160);         // 196,608 B
    uint4*  wf3 = (uint4*)(ws + 127008768);         // 196,608 B
    float* hsum = (float*)(ws + 127205376);         // 327,680 B (end ~127.5 MB)

    // LDS: 11 spike rows + 48KB A-plane
    constexpr int LDS2 = 11 * 46 * MSTR + 49152;    // 68,816 + 49,152 = 117,968
    constexpr int LDS3 = 11 * 58 * MSTR + 49152;    // 86,768 + 49,152 = 135,920
    static bool attr_set = false;
    if (!attr_set) {
        hipFuncSetAttribute((const void*)&convL<4, 6, 3, 3, 46, 4, 16>,
                            hipFuncAttributeMaxDynamicSharedMemorySize, LDS2);
        hipFuncSetAttribute((const void*)&convL<16, 24, 9, 9, 58, 16, 20>,
                            hipFuncAttributeMaxDynamicSharedMemorySize, LDS3);
        attr_set = true;
    }

    prep_wfrag2<<<96, 256, 0, stream>>>(w2, w3, wf2, wf3);

    conv1_lif1<<<dim3(10, 32), 256, 0, stream>>>(x, w1, s1);

    convL<4, 6, 3, 3, 46, 4, 16><<<dim3(17, 32, 2), 256, LDS2, stream>>>(s1, wf2, uh, ul);
    lif_spikes<<<320, 256, 0, stream>>>(uh, ul, s2);

    convL<16, 24, 9, 9, 58, 16, 20><<<dim3(17, 32, 2), 256, LDS3, stream>>>(s2, wf3, uh, ul);
    lif_sum<<<320, 256, 0, stream>>>(uh, ul, hsum);

    fc_out<<<32, 256, 0, stream>>>(hsum, wf, bf, out);
}